// Round 8
// baseline (147.758 us; speedup 1.0000x reference)
//
#include <hip/hip_runtime.h>
#include <hip/hip_bf16.h>
#include <math.h>

// Problem constants
#define BATCH   2048
#define TWO_B   4096
#define DIM     1024
#define NBLK4   256           // 16x16 grid of 256x256 tiles
#define RBLK    32            // reduce blocks
// 1 / (0.07 * ln(2)) : exp(s/T) = exp2(s * INV_T_LOG2E)
#define INV_T_LOG2E 20.60991907f
#define INV_T       14.285714285714286f
#define INV_127SQ   6.200013640958517e-05f   // 1/(127*127)

typedef float f32x4 __attribute__((ext_vector_type(4)));
typedef int   i32x4 __attribute__((ext_vector_type(4)));

// R21: diagnostic round. Cross-round arithmetic (MfmaUtil x dur vs the
// invariant ~5200 MFMA cycles/SIMD) implies SCLK ~850 MHz during gemm in
// R17/R18/R19 — would explain the entire 42-61 us plateau across five
// structurally different GEMMs. probe_kernel below measures SCLK directly:
// 28672 dependent FMAs = 114688 cycles; dur = 114.7kcyc / SCLK.
__device__ __attribute__((aligned(4096))) char g_z[(size_t)TWO_B * DIM]; // i8, 4 MB
__device__ __attribute__((aligned(256))) float g_part[TWO_B][32];        // 512 KB
__device__ float        g_positives[TWO_B];
__device__ float        g_loss;
__device__ unsigned int g_counter;
__device__ float        g_probe;

__device__ __forceinline__ void load_lds16(const void* g, void* l) {
    __builtin_amdgcn_global_load_lds(
        (const __attribute__((address_space(1))) void*)g,
        (__attribute__((address_space(3))) void*)l,
        16, 0, 0);
}

// ---------------------------------------------------------------------------
// Kernel 1: L2-normalize 4096 rows -> int8 q[4096][1024] (4 MB).
// Wave-per-row; block 0 zero-inits loss accumulator + completion counter.
// ---------------------------------------------------------------------------
__global__ __launch_bounds__(256) void normalize_kernel(
        const float* __restrict__ feat) {
    const int lane = threadIdx.x & 63;
    const int row  = blockIdx.x * 4 + (threadIdx.x >> 6);
    if (blockIdx.x == 0 && threadIdx.x == 0) { g_loss = 0.0f; g_counter = 0u; }

    const float* src = feat + (row < BATCH ? (size_t)row * (2 * DIM)
                                           : (size_t)(row - BATCH) * (2 * DIM) + DIM);
    float4 v[4];
    float ss = 0.0f;
    #pragma unroll
    for (int t = 0; t < 4; ++t) {
        v[t] = ((const float4*)src)[t * 64 + lane];
        ss += v[t].x * v[t].x + v[t].y * v[t].y + v[t].z * v[t].z + v[t].w * v[t].w;
    }
    #pragma unroll
    for (int off = 32; off; off >>= 1) ss += __shfl_xor(ss, off, 64);
    const float s127 = 127.0f / fmaxf(sqrtf(ss), 1e-12f);
    int4 o;
    int* op = (int*)&o;
    #pragma unroll
    for (int t = 0; t < 4; ++t) {
        const int b0 = __float2int_rn(v[t].x * s127) & 255;
        const int b1 = __float2int_rn(v[t].y * s127) & 255;
        const int b2 = __float2int_rn(v[t].z * s127) & 255;
        const int b3 = __float2int_rn(v[t].w * s127) & 255;
        op[t] = b0 | (b1 << 8) | (b2 << 16) | (b3 << 24);
    }
    ((int4*)(g_z + (size_t)row * DIM))[lane] = o;   // 64 lanes x 16 B = one row
}

// ---------------------------------------------------------------------------
// Kernel 2: sim = (q q^T)/127^2 via mfma_i32_16x16x64_i8 — EXACT R20 body
// (atomic-free epilogue, plain uncontended stores to g_part/g_positives).
// ---------------------------------------------------------------------------
__global__ __launch_bounds__(512) void gemm_fused() {
    __shared__ char smem[65536];     // buf: [sA 16K | sB 16K] x2

    // XCD-aware swizzle: id&7 = round-robin XCD; 4x8-tile region per XCD
    const int bid = blockIdx.x;
    const int xcd = bid & 7;
    const int t5  = bid >> 3;                   // 0..31 within region
    const int by  = (xcd >> 1) * 4 + (t5 & 3);
    const int bx  = (xcd & 1) * 8 + (t5 >> 2);
    const int rb  = by * 256;
    const int cb  = bx * 256;

    const int tid  = threadIdx.x;
    const int lane = tid & 63;
    const int wv   = tid >> 6;       // wave 0..7
    const int wr   = wv & 3;         // wave row (0..3) -> 64-row subtile
    const int wc   = wv >> 2;        // wave col (0..1) -> 128-col subtile
    const int q    = lane >> 4;      // quad 0..3
    const int mn   = lane & 15;

    i32x4 acc[4][8] = {};            // i32 accumulators (exact)

    const int lrow  = lane >> 2;                       // row within 16-row chunk
    const int lsegb = ((lane & 3) ^ ((lane >> 3) & 3)) * 16;   // fetch-side XOR swizzle
    const int rslot = (q ^ ((mn >> 1) & 3)) * 16;      // byte offset in 64-B row

    // staging: 32 chunks of 16 rows x 64 B (A: ci 0..15, B: ci 16..31);
    // wave wv stages ci = 4wv..4wv+3.
    size_t goff[4];
    int    loff[4];
    #pragma unroll
    for (int t = 0; t < 4; ++t) {
        const int ci = wv * 4 + t;
        const bool isB = ci >= 16;
        const int  cc  = ci & 15;
        goff[t] = (size_t)((isB ? cb : rb) + cc * 16 + lrow) * DIM + lsegb;
        loff[t] = (isB ? 16384 : 0) + cc * 1024;
    }

    // preload K-tile 0 into buffer 0
    #pragma unroll
    for (int t = 0; t < 4; ++t)
        load_lds16(g_z + goff[t], smem + loff[t]);
    __syncthreads();

    int cur = 0;
    for (int k0 = 64; k0 <= DIM; k0 += 64) {
        if (k0 < DIM) {   // prefetch next K-tile into the other buffer
            const int nxt = cur ^ 1;
            #pragma unroll
            for (int t = 0; t < 4; ++t)
                load_lds16(g_z + goff[t] + k0, smem + nxt * 32768 + loff[t]);
        }
        const char* cA = smem + cur * 32768;
        const char* cB = cA + 16384;

        i32x4 af[4], bf[8];
        #pragma unroll
        for (int i = 0; i < 4; ++i)
            af[i] = *(const i32x4*)&cA[(wr * 64 + i * 16 + mn) * 64 + rslot];
        #pragma unroll
        for (int j = 0; j < 8; ++j)
            bf[j] = *(const i32x4*)&cB[(wc * 128 + j * 16 + mn) * 64 + rslot];
        #pragma unroll
        for (int i = 0; i < 4; ++i)
            #pragma unroll
            for (int j = 0; j < 8; ++j)
                acc[i][j] = __builtin_amdgcn_mfma_i32_16x16x64_i8(
                                af[i], bf[j], acc[i][j], 0, 0, 0);
        __syncthreads();
        cur ^= 1;
    }

    // ---- Epilogue: exp-sum partials, plain uncontended stores ----
    const int slot = bx * 2 + wc;    // 0..31, unique per (col-tile, half)
    #pragma unroll
    for (int i = 0; i < 4; ++i) {
        #pragma unroll
        for (int reg = 0; reg < 4; ++reg) {
            const int r  = rb + wr * 64 + i * 16 + q * 4 + reg;
            const int pc = (r + BATCH) & (TWO_B - 1);
            float local = 0.0f;
            #pragma unroll
            for (int j = 0; j < 8; ++j) {
                const int c = cb + wc * 128 + j * 16 + mn;
                const float s = (float)acc[i][j][reg] * INV_127SQ;
                if (c == pc)   // unique writer per r across the whole grid
                    g_positives[r] = s;
                local += (c == r) ? 0.0f : exp2f(s * INV_T_LOG2E);
            }
            local += __shfl_xor(local, 1, 64);
            local += __shfl_xor(local, 2, 64);
            local += __shfl_xor(local, 4, 64);
            local += __shfl_xor(local, 8, 64);
            if (mn == 0) g_part[r][slot] = local;   // unique (r, slot)
        }
    }
}

// ---------------------------------------------------------------------------
// Kernel 3 (R21): parallel reduce — 32 blocks x 128 threads, one row per
// thread (8x float4 = 128 B contiguous per thread). Proven finalize tail:
// 32 agent-scope atomicAdds into g_loss + relaxed counter, last block
// writes out[0]. Replaces R20's single-block reduce (~10 us -> ~3 us).
// ---------------------------------------------------------------------------
__global__ __launch_bounds__(128) void reduce_kernel(float* __restrict__ out) {
    const int tid = threadIdx.x;
    const int r   = blockIdx.x * 128 + tid;
    const float4* pr = (const float4*)g_part[r];
    float s = 0.0f;
    #pragma unroll
    for (int u = 0; u < 8; ++u) {
        const float4 v = pr[u];
        s += v.x + v.y + v.z + v.w;
    }
    float acc = logf(s) - g_positives[r] * INV_T;
    #pragma unroll
    for (int off = 32; off; off >>= 1) acc += __shfl_down(acc, off, 64);
    __shared__ float sp[2];
    __shared__ int amLast;
    if ((tid & 63) == 0) sp[tid >> 6] = acc;
    __syncthreads();
    if (tid == 0) {
        atomicAdd(&g_loss, sp[0] + sp[1]);
        unsigned int old = __hip_atomic_fetch_add(&g_counter, 1u, __ATOMIC_RELAXED,
                                                  __HIP_MEMORY_SCOPE_AGENT);
        amLast = (old == RBLK - 1);
    }
    __syncthreads();
    if (amLast && tid == 0)
        out[0] = __hip_atomic_load(&g_loss, __ATOMIC_RELAXED,
                                   __HIP_MEMORY_SCOPE_AGENT) * (1.0f / TWO_B);
}

// ---------------------------------------------------------------------------
// Kernel 4 (R21): SCLK probe. 28672 dependent v_fma_f32 (4 cyc each, m07)
// = 114688 cycles in a single wave. rocprof dur gives SCLK directly:
//   ~48 us  -> 2.4 GHz (no throttle; plateau is real stalling)
//   ~135 us -> ~850 MHz (throttle confirmed; strategy = fewer cycles/fusion)
// asm "+v" barrier every 28 FMAs keeps the chain dependent and live.
// ---------------------------------------------------------------------------
__global__ __launch_bounds__(64) void probe_kernel() {
    float x = g_positives[0];        // runtime value, ~[-1,1]
    const float a = 1.0000001f, b = 1e-7f;
    for (int it = 0; it < 1024; ++it) {
        #pragma unroll
        for (int u = 0; u < 28; ++u) x = __builtin_fmaf(a, x, b);
        asm volatile("" : "+v"(x));
    }
    if (threadIdx.x == 0) g_probe = x;
}

extern "C" void kernel_launch(void* const* d_in, const int* in_sizes, int n_in,
                              void* d_out, int out_size, void* d_ws, size_t ws_size,
                              hipStream_t stream) {
    const float* feat = (const float*)d_in[0];
    float* out = (float*)d_out;
    (void)d_ws; (void)ws_size;   // poison fill is unconditional (R14) — ws unused

    normalize_kernel<<<TWO_B / 4, 256, 0, stream>>>(feat);
    gemm_fused<<<NBLK4, 512, 0, stream>>>();
    reduce_kernel<<<RBLK, 128, 0, stream>>>(out);
    probe_kernel<<<1, 64, 0, stream>>>();
}

// Round 9
// 118.025 us; speedup vs baseline: 1.2519x; 1.2519x over previous
//
#include <hip/hip_runtime.h>
#include <hip/hip_bf16.h>
#include <math.h>

// Problem constants
#define BATCH   2048
#define TWO_B   4096
#define DIM     1024
#define NBLK4   256           // 16x16 grid of 256x256 tiles
#define RBLK    32            // reduce blocks
// 1 / (0.07 * ln(2)) : exp(s/T) = exp2(s * INV_T_LOG2E)
#define INV_T_LOG2E 20.60991907f
#define INV_T       14.285714285714286f
#define INV_127SQ   6.200013640958517e-05f   // 1/(127*127)

typedef float f32x4 __attribute__((ext_vector_type(4)));
typedef int   i32x4 __attribute__((ext_vector_type(4)));

// R22: main path = R21 minus probe (best-known-good, ~88 us expected).
// Probe verdict (R21): SCLK ~1.9-2.4 GHz during our window — throttle
// theory DEAD; gfx94x-fallback MfmaUtil is just miscalibrated for i8.
// Remaining mystery: gemm ~36 us vs ~14-20 us static model. shadow_kernel
// below is a within-round ablation: the gemm K-loop body (ds_read + MFMA +
// barrier, exact geometry) with staging REMOVED, x3. X = shadow/3 splits
// the gemm cost into {LDS+MFMA} vs {staging/drain} decisively.
__device__ __attribute__((aligned(4096))) char g_z[(size_t)TWO_B * DIM]; // i8, 4 MB
__device__ __attribute__((aligned(256))) float g_part[TWO_B][32];        // 512 KB
__device__ float        g_positives[TWO_B];
__device__ float        g_loss;
__device__ unsigned int g_counter;
__device__ int          g_shadow[NBLK4 * 512];                           // dummy sink

__device__ __forceinline__ void load_lds16(const void* g, void* l) {
    __builtin_amdgcn_global_load_lds(
        (const __attribute__((address_space(1))) void*)g,
        (__attribute__((address_space(3))) void*)l,
        16, 0, 0);
}

// ---------------------------------------------------------------------------
// Kernel 1: L2-normalize 4096 rows -> int8 q[4096][1024] (4 MB).
// Wave-per-row; block 0 zero-inits loss accumulator + completion counter.
// ---------------------------------------------------------------------------
__global__ __launch_bounds__(256) void normalize_kernel(
        const float* __restrict__ feat) {
    const int lane = threadIdx.x & 63;
    const int row  = blockIdx.x * 4 + (threadIdx.x >> 6);
    if (blockIdx.x == 0 && threadIdx.x == 0) { g_loss = 0.0f; g_counter = 0u; }

    const float* src = feat + (row < BATCH ? (size_t)row * (2 * DIM)
                                           : (size_t)(row - BATCH) * (2 * DIM) + DIM);
    float4 v[4];
    float ss = 0.0f;
    #pragma unroll
    for (int t = 0; t < 4; ++t) {
        v[t] = ((const float4*)src)[t * 64 + lane];
        ss += v[t].x * v[t].x + v[t].y * v[t].y + v[t].z * v[t].z + v[t].w * v[t].w;
    }
    #pragma unroll
    for (int off = 32; off; off >>= 1) ss += __shfl_xor(ss, off, 64);
    const float s127 = 127.0f / fmaxf(sqrtf(ss), 1e-12f);
    int4 o;
    int* op = (int*)&o;
    #pragma unroll
    for (int t = 0; t < 4; ++t) {
        const int b0 = __float2int_rn(v[t].x * s127) & 255;
        const int b1 = __float2int_rn(v[t].y * s127) & 255;
        const int b2 = __float2int_rn(v[t].z * s127) & 255;
        const int b3 = __float2int_rn(v[t].w * s127) & 255;
        op[t] = b0 | (b1 << 8) | (b2 << 16) | (b3 << 24);
    }
    ((int4*)(g_z + (size_t)row * DIM))[lane] = o;   // 64 lanes x 16 B = one row
}

// ---------------------------------------------------------------------------
// Kernel 2: sim = (q q^T)/127^2 via mfma_i32_16x16x64_i8 — EXACT R20 body
// (atomic-free epilogue, plain uncontended stores to g_part/g_positives).
// ---------------------------------------------------------------------------
__global__ __launch_bounds__(512) void gemm_fused() {
    __shared__ char smem[65536];     // buf: [sA 16K | sB 16K] x2

    // XCD-aware swizzle: id&7 = round-robin XCD; 4x8-tile region per XCD
    const int bid = blockIdx.x;
    const int xcd = bid & 7;
    const int t5  = bid >> 3;                   // 0..31 within region
    const int by  = (xcd >> 1) * 4 + (t5 & 3);
    const int bx  = (xcd & 1) * 8 + (t5 >> 2);
    const int rb  = by * 256;
    const int cb  = bx * 256;

    const int tid  = threadIdx.x;
    const int lane = tid & 63;
    const int wv   = tid >> 6;       // wave 0..7
    const int wr   = wv & 3;         // wave row (0..3) -> 64-row subtile
    const int wc   = wv >> 2;        // wave col (0..1) -> 128-col subtile
    const int q    = lane >> 4;      // quad 0..3
    const int mn   = lane & 15;

    i32x4 acc[4][8] = {};            // i32 accumulators (exact)

    const int lrow  = lane >> 2;                       // row within 16-row chunk
    const int lsegb = ((lane & 3) ^ ((lane >> 3) & 3)) * 16;   // fetch-side XOR swizzle
    const int rslot = (q ^ ((mn >> 1) & 3)) * 16;      // byte offset in 64-B row

    // staging: 32 chunks of 16 rows x 64 B (A: ci 0..15, B: ci 16..31);
    // wave wv stages ci = 4wv..4wv+3.
    size_t goff[4];
    int    loff[4];
    #pragma unroll
    for (int t = 0; t < 4; ++t) {
        const int ci = wv * 4 + t;
        const bool isB = ci >= 16;
        const int  cc  = ci & 15;
        goff[t] = (size_t)((isB ? cb : rb) + cc * 16 + lrow) * DIM + lsegb;
        loff[t] = (isB ? 16384 : 0) + cc * 1024;
    }

    // preload K-tile 0 into buffer 0
    #pragma unroll
    for (int t = 0; t < 4; ++t)
        load_lds16(g_z + goff[t], smem + loff[t]);
    __syncthreads();

    int cur = 0;
    for (int k0 = 64; k0 <= DIM; k0 += 64) {
        if (k0 < DIM) {   // prefetch next K-tile into the other buffer
            const int nxt = cur ^ 1;
            #pragma unroll
            for (int t = 0; t < 4; ++t)
                load_lds16(g_z + goff[t] + k0, smem + nxt * 32768 + loff[t]);
        }
        const char* cA = smem + cur * 32768;
        const char* cB = cA + 16384;

        i32x4 af[4], bf[8];
        #pragma unroll
        for (int i = 0; i < 4; ++i)
            af[i] = *(const i32x4*)&cA[(wr * 64 + i * 16 + mn) * 64 + rslot];
        #pragma unroll
        for (int j = 0; j < 8; ++j)
            bf[j] = *(const i32x4*)&cB[(wc * 128 + j * 16 + mn) * 64 + rslot];
        #pragma unroll
        for (int i = 0; i < 4; ++i)
            #pragma unroll
            for (int j = 0; j < 8; ++j)
                acc[i][j] = __builtin_amdgcn_mfma_i32_16x16x64_i8(
                                af[i], bf[j], acc[i][j], 0, 0, 0);
        __syncthreads();
        cur ^= 1;
    }

    // ---- Epilogue: exp-sum partials, plain uncontended stores ----
    const int slot = bx * 2 + wc;    // 0..31, unique per (col-tile, half)
    #pragma unroll
    for (int i = 0; i < 4; ++i) {
        #pragma unroll
        for (int reg = 0; reg < 4; ++reg) {
            const int r  = rb + wr * 64 + i * 16 + q * 4 + reg;
            const int pc = (r + BATCH) & (TWO_B - 1);
            float local = 0.0f;
            #pragma unroll
            for (int j = 0; j < 8; ++j) {
                const int c = cb + wc * 128 + j * 16 + mn;
                const float s = (float)acc[i][j][reg] * INV_127SQ;
                if (c == pc)   // unique writer per r across the whole grid
                    g_positives[r] = s;
                local += (c == r) ? 0.0f : exp2f(s * INV_T_LOG2E);
            }
            local += __shfl_xor(local, 1, 64);
            local += __shfl_xor(local, 2, 64);
            local += __shfl_xor(local, 4, 64);
            local += __shfl_xor(local, 8, 64);
            if (mn == 0) g_part[r][slot] = local;   // unique (r, slot)
        }
    }
}

// ---------------------------------------------------------------------------
// Kernel 3: parallel reduce — 32 blocks x 128 threads, one row per thread.
// Finalize tail: 32 agent-scope atomicAdds + relaxed counter (proven).
// ---------------------------------------------------------------------------
__global__ __launch_bounds__(128) void reduce_kernel(float* __restrict__ out) {
    const int tid = threadIdx.x;
    const int r   = blockIdx.x * 128 + tid;
    const float4* pr = (const float4*)g_part[r];
    float s = 0.0f;
    #pragma unroll
    for (int u = 0; u < 8; ++u) {
        const float4 v = pr[u];
        s += v.x + v.y + v.z + v.w;
    }
    float acc = logf(s) - g_positives[r] * INV_T;
    #pragma unroll
    for (int off = 32; off; off >>= 1) acc += __shfl_down(acc, off, 64);
    __shared__ float sp[2];
    __shared__ int amLast;
    if ((tid & 63) == 0) sp[tid >> 6] = acc;
    __syncthreads();
    if (tid == 0) {
        atomicAdd(&g_loss, sp[0] + sp[1]);
        unsigned int old = __hip_atomic_fetch_add(&g_counter, 1u, __ATOMIC_RELAXED,
                                                  __HIP_MEMORY_SCOPE_AGENT);
        amLast = (old == RBLK - 1);
    }
    __syncthreads();
    if (amLast && tid == 0)
        out[0] = __hip_atomic_load(&g_loss, __ATOMIC_RELAXED,
                                   __HIP_MEMORY_SCOPE_AGENT) * (1.0f / TWO_B);
}

// ---------------------------------------------------------------------------
// Kernel 4 (R22): shadow ablation. EXACT gemm K-loop body (same geometry,
// same 12 ds_read_b128 + 32 MFMA + __syncthreads per tile, same dbuf
// alternation) with staging REMOVED: LDS pre-filled once, then 3 x 16 tiles.
// dur = 3X where X = pure {LDS+MFMA+barrier} cost of one 16-tile pass.
//   X <= 14 us -> gemm's residual is staging/drain -> restructure staging.
//   X >= 20 us -> LDS/MFMA interleave is the cost -> 32x32x32 i8 port.
// Writes only g_shadow (acc kept live via the sum-store; no DCE).
// ---------------------------------------------------------------------------
__global__ __launch_bounds__(512) void shadow_kernel() {
    __shared__ char smem[65536];
    const int bid = blockIdx.x;
    const int xcd = bid & 7;
    const int t5  = bid >> 3;
    const int by  = (xcd >> 1) * 4 + (t5 & 3);
    const int bx  = (xcd & 1) * 8 + (t5 >> 2);
    const int rb  = by * 256;
    const int cb  = bx * 256;

    const int tid  = threadIdx.x;
    const int lane = tid & 63;
    const int wv   = tid >> 6;
    const int wr   = wv & 3;
    const int wc   = wv >> 2;
    const int q    = lane >> 4;
    const int mn   = lane & 15;

    i32x4 acc[4][8] = {};

    const int lrow  = lane >> 2;
    const int lsegb = ((lane & 3) ^ ((lane >> 3) & 3)) * 16;
    const int rslot = (q ^ ((mn >> 1) & 3)) * 16;

    size_t goff[4];
    int    loff[4];
    #pragma unroll
    for (int t = 0; t < 4; ++t) {
        const int ci = wv * 4 + t;
        const bool isB = ci >= 16;
        const int  cc  = ci & 15;
        goff[t] = (size_t)((isB ? cb : rb) + cc * 16 + lrow) * DIM + lsegb;
        loff[t] = (isB ? 16384 : 0) + cc * 1024;
    }

    // prefill BOTH buffers once (K-tiles 0 and 1), then never stage again
    #pragma unroll
    for (int b = 0; b < 2; ++b)
        #pragma unroll
        for (int t = 0; t < 4; ++t)
            load_lds16(g_z + goff[t] + b * 64, smem + b * 32768 + loff[t]);
    __syncthreads();

    for (int rep = 0; rep < 3; ++rep) {
        for (int t = 0; t < 16; ++t) {
            const char* cA = smem + (t & 1) * 32768;
            const char* cB = cA + 16384;
            i32x4 af[4], bf[8];
            #pragma unroll
            for (int i = 0; i < 4; ++i)
                af[i] = *(const i32x4*)&cA[(wr * 64 + i * 16 + mn) * 64 + rslot];
            #pragma unroll
            for (int j = 0; j < 8; ++j)
                bf[j] = *(const i32x4*)&cB[(wc * 128 + j * 16 + mn) * 64 + rslot];
            #pragma unroll
            for (int i = 0; i < 4; ++i)
                #pragma unroll
                for (int j = 0; j < 8; ++j)
                    acc[i][j] = __builtin_amdgcn_mfma_i32_16x16x64_i8(
                                    af[i], bf[j], acc[i][j], 0, 0, 0);
            __syncthreads();
        }
    }

    int s = 0;
    #pragma unroll
    for (int i = 0; i < 4; ++i)
        #pragma unroll
        for (int j = 0; j < 8; ++j)
            #pragma unroll
            for (int reg = 0; reg < 4; ++reg)
                s += acc[i][j][reg];
    g_shadow[bid * 512 + tid] = s;   // keeps every acc live
}

extern "C" void kernel_launch(void* const* d_in, const int* in_sizes, int n_in,
                              void* d_out, int out_size, void* d_ws, size_t ws_size,
                              hipStream_t stream) {
    const float* feat = (const float*)d_in[0];
    float* out = (float*)d_out;
    (void)d_ws; (void)ws_size;   // poison fill is unconditional (R14) — ws unused

    normalize_kernel<<<TWO_B / 4, 256, 0, stream>>>(feat);
    gemm_fused<<<NBLK4, 512, 0, stream>>>();
    reduce_kernel<<<RBLK, 128, 0, stream>>>(out);
    shadow_kernel<<<NBLK4, 512, 0, stream>>>();   // diagnostic, after main path
}

// Round 10
// 86.861 us; speedup vs baseline: 1.7011x; 1.3588x over previous
//
#include <hip/hip_runtime.h>
#include <hip/hip_bf16.h>
#include <math.h>

// Problem constants
#define BATCH   2048
#define TWO_B   4096
#define DIM     1024
#define NBLK4   256           // 16x16 grid of 256x256 tiles
#define RBLK    32            // reduce blocks
// 1 / (0.07 * ln(2)) : exp(s/T) = exp2(s * INV_T_LOG2E)
#define INV_T_LOG2E 20.60991907f
#define INV_T       14.285714285714286f
#define INV_127SQ   6.200013640958517e-05f   // 1/(127*127)

typedef float f32x4 __attribute__((ext_vector_type(4)));
typedef int   i32x4 __attribute__((ext_vector_type(4)));

// R23: counted-vmcnt staging on the proven 2-phase body.
// R22 ablation: pure {12 ds_read_b128 + 32 MFMA + barrier} x16 = X ~9.5 us;
// gemm = ~36 us => ~26 us is the staging path — specifically the implicit
// vmcnt(0) drain __syncthreads emits, which flushes the just-issued
// prefetch every tile. Fix (single variable vs R20 body): 3 LDS buffers
// (96 KB), prefetch depth 2, raw s_barrier with vmcnt(4)+lgkmcnt(0)
// (vmcnt never 0 until the t=14 tail). Wait derivation: at end of iter t
// newest outstanding = tile t+2's 4 loads -> vmcnt(4) guarantees tile t+1
// resident; WAR on buffer reuse protected by lgkmcnt(0) at each barrier.
__device__ __attribute__((aligned(4096))) char g_z[(size_t)TWO_B * DIM]; // i8, 4 MB
__device__ __attribute__((aligned(256))) float g_part[TWO_B][32];        // 512 KB
__device__ float        g_positives[TWO_B];
__device__ float        g_loss;
__device__ unsigned int g_counter;

__device__ __forceinline__ void load_lds16(const void* g, void* l) {
    __builtin_amdgcn_global_load_lds(
        (const __attribute__((address_space(1))) void*)g,
        (__attribute__((address_space(3))) void*)l,
        16, 0, 0);
}

// ---------------------------------------------------------------------------
// Kernel 1: L2-normalize 4096 rows -> int8 q[4096][1024] (4 MB).
// Wave-per-row; block 0 zero-inits loss accumulator + completion counter.
// ---------------------------------------------------------------------------
__global__ __launch_bounds__(256) void normalize_kernel(
        const float* __restrict__ feat) {
    const int lane = threadIdx.x & 63;
    const int row  = blockIdx.x * 4 + (threadIdx.x >> 6);
    if (blockIdx.x == 0 && threadIdx.x == 0) { g_loss = 0.0f; g_counter = 0u; }

    const float* src = feat + (row < BATCH ? (size_t)row * (2 * DIM)
                                           : (size_t)(row - BATCH) * (2 * DIM) + DIM);
    float4 v[4];
    float ss = 0.0f;
    #pragma unroll
    for (int t = 0; t < 4; ++t) {
        v[t] = ((const float4*)src)[t * 64 + lane];
        ss += v[t].x * v[t].x + v[t].y * v[t].y + v[t].z * v[t].z + v[t].w * v[t].w;
    }
    #pragma unroll
    for (int off = 32; off; off >>= 1) ss += __shfl_xor(ss, off, 64);
    const float s127 = 127.0f / fmaxf(sqrtf(ss), 1e-12f);
    int4 o;
    int* op = (int*)&o;
    #pragma unroll
    for (int t = 0; t < 4; ++t) {
        const int b0 = __float2int_rn(v[t].x * s127) & 255;
        const int b1 = __float2int_rn(v[t].y * s127) & 255;
        const int b2 = __float2int_rn(v[t].z * s127) & 255;
        const int b3 = __float2int_rn(v[t].w * s127) & 255;
        op[t] = b0 | (b1 << 8) | (b2 << 16) | (b3 << 24);
    }
    ((int4*)(g_z + (size_t)row * DIM))[lane] = o;   // 64 lanes x 16 B = one row
}

// ---------------------------------------------------------------------------
// Kernel 2 (R23): sim = (q q^T)/127^2 via mfma_i32_16x16x64_i8.
// Body identical to R20 (atomic-free epilogue) EXCEPT the K-loop sync:
// 3-buffer, depth-2 prefetch, counted vmcnt — see header comment.
// ---------------------------------------------------------------------------
__global__ __launch_bounds__(512) void gemm_fused() {
    __shared__ char smem[98304];     // 3 buffers x 32 KB [sA 16K | sB 16K]

    // XCD-aware swizzle: id&7 = round-robin XCD; 4x8-tile region per XCD
    const int bid = blockIdx.x;
    const int xcd = bid & 7;
    const int t5  = bid >> 3;                   // 0..31 within region
    const int by  = (xcd >> 1) * 4 + (t5 & 3);
    const int bx  = (xcd & 1) * 8 + (t5 >> 2);
    const int rb  = by * 256;
    const int cb  = bx * 256;

    const int tid  = threadIdx.x;
    const int lane = tid & 63;
    const int wv   = tid >> 6;       // wave 0..7
    const int wr   = wv & 3;         // wave row (0..3) -> 64-row subtile
    const int wc   = wv >> 2;        // wave col (0..1) -> 128-col subtile
    const int q    = lane >> 4;      // quad 0..3
    const int mn   = lane & 15;

    i32x4 acc[4][8] = {};            // i32 accumulators (exact)

    const int lrow  = lane >> 2;                       // row within 16-row chunk
    const int lsegb = ((lane & 3) ^ ((lane >> 3) & 3)) * 16;   // fetch-side XOR swizzle
    const int rslot = (q ^ ((mn >> 1) & 3)) * 16;      // byte offset in 64-B row

    // staging: 32 chunks of 16 rows x 64 B (A: ci 0..15, B: ci 16..31);
    // wave wv stages ci = 4wv..4wv+3.
    size_t goff[4];
    int    loff[4];
    #pragma unroll
    for (int t = 0; t < 4; ++t) {
        const int ci = wv * 4 + t;
        const bool isB = ci >= 16;
        const int  cc  = ci & 15;
        goff[t] = (size_t)((isB ? cb : rb) + cc * 16 + lrow) * DIM + lsegb;
        loff[t] = (isB ? 16384 : 0) + cc * 1024;
    }

    // ---- prologue: stage tiles 0,1 into buffers 0,1; wait tile 0 only ----
    #pragma unroll
    for (int b = 0; b < 2; ++b)
        #pragma unroll
        for (int t = 0; t < 4; ++t)
            load_lds16(g_z + goff[t] + b * 64, smem + b * 32768 + loff[t]);
    asm volatile("s_waitcnt vmcnt(4)" ::: "memory");   // tile 0 resident
    __builtin_amdgcn_s_barrier();

    int cur = 0;                     // buffer holding tile t
    for (int t = 0; t < 16; ++t) {
        const char* cA = smem + cur * 32768;
        const char* cB = cA + 16384;

        i32x4 af[4], bf[8];
        #pragma unroll
        for (int i = 0; i < 4; ++i)
            af[i] = *(const i32x4*)&cA[(wr * 64 + i * 16 + mn) * 64 + rslot];
        #pragma unroll
        for (int j = 0; j < 8; ++j)
            bf[j] = *(const i32x4*)&cB[(wc * 128 + j * 16 + mn) * 64 + rslot];

        if (t + 2 < 16) {            // stage tile t+2 into buf (cur+2)%3
            const int bs = cur >= 1 ? cur - 1 : 2;
            #pragma unroll
            for (int tt = 0; tt < 4; ++tt)
                load_lds16(g_z + goff[tt] + (t + 2) * 64,
                           smem + bs * 32768 + loff[tt]);
        }

        #pragma unroll
        for (int i = 0; i < 4; ++i)
            #pragma unroll
            for (int j = 0; j < 8; ++j)
                acc[i][j] = __builtin_amdgcn_mfma_i32_16x16x64_i8(
                                af[i], bf[j], acc[i][j], 0, 0, 0);

        if (t < 15) {
            // tile t+1 must be resident past this barrier; newest in-flight
            // loads are tile t+2's 4 (none issued at t=14 -> drain 0).
            if (t < 14) asm volatile("s_waitcnt vmcnt(4) lgkmcnt(0)" ::: "memory");
            else        asm volatile("s_waitcnt vmcnt(0) lgkmcnt(0)" ::: "memory");
            __builtin_amdgcn_s_barrier();
        }
        cur = cur == 2 ? 0 : cur + 1;
    }

    // ---- Epilogue: exp-sum partials, plain uncontended stores ----
    const int slot = bx * 2 + wc;    // 0..31, unique per (col-tile, half)
    #pragma unroll
    for (int i = 0; i < 4; ++i) {
        #pragma unroll
        for (int reg = 0; reg < 4; ++reg) {
            const int r  = rb + wr * 64 + i * 16 + q * 4 + reg;
            const int pc = (r + BATCH) & (TWO_B - 1);
            float local = 0.0f;
            #pragma unroll
            for (int j = 0; j < 8; ++j) {
                const int c = cb + wc * 128 + j * 16 + mn;
                const float s = (float)acc[i][j][reg] * INV_127SQ;
                if (c == pc)   // unique writer per r across the whole grid
                    g_positives[r] = s;
                local += (c == r) ? 0.0f : exp2f(s * INV_T_LOG2E);
            }
            local += __shfl_xor(local, 1, 64);
            local += __shfl_xor(local, 2, 64);
            local += __shfl_xor(local, 4, 64);
            local += __shfl_xor(local, 8, 64);
            if (mn == 0) g_part[r][slot] = local;   // unique (r, slot)
        }
    }
}

// ---------------------------------------------------------------------------
// Kernel 3: parallel reduce — 32 blocks x 128 threads, one row per thread.
// Finalize tail: 32 agent-scope atomicAdds + relaxed counter (proven).
// ---------------------------------------------------------------------------
__global__ __launch_bounds__(128) void reduce_kernel(float* __restrict__ out) {
    const int tid = threadIdx.x;
    const int r   = blockIdx.x * 128 + tid;
    const float4* pr = (const float4*)g_part[r];
    float s = 0.0f;
    #pragma unroll
    for (int u = 0; u < 8; ++u) {
        const float4 v = pr[u];
        s += v.x + v.y + v.z + v.w;
    }
    float acc = logf(s) - g_positives[r] * INV_T;
    #pragma unroll
    for (int off = 32; off; off >>= 1) acc += __shfl_down(acc, off, 64);
    __shared__ float sp[2];
    __shared__ int amLast;
    if ((tid & 63) == 0) sp[tid >> 6] = acc;
    __syncthreads();
    if (tid == 0) {
        atomicAdd(&g_loss, sp[0] + sp[1]);
        unsigned int old = __hip_atomic_fetch_add(&g_counter, 1u, __ATOMIC_RELAXED,
                                                  __HIP_MEMORY_SCOPE_AGENT);
        amLast = (old == RBLK - 1);
    }
    __syncthreads();
    if (amLast && tid == 0)
        out[0] = __hip_atomic_load(&g_loss, __ATOMIC_RELAXED,
                                   __HIP_MEMORY_SCOPE_AGENT) * (1.0f / TWO_B);
}

extern "C" void kernel_launch(void* const* d_in, const int* in_sizes, int n_in,
                              void* d_out, int out_size, void* d_ws, size_t ws_size,
                              hipStream_t stream) {
    const float* feat = (const float*)d_in[0];
    float* out = (float*)d_out;
    (void)d_ws; (void)ws_size;   // poison fill is unconditional (R14) — ws unused

    normalize_kernel<<<TWO_B / 4, 256, 0, stream>>>(feat);
    gemm_fused<<<NBLK4, 512, 0, stream>>>();
    reduce_kernel<<<RBLK, 128, 0, stream>>>(out);
}

// Round 11
// 83.923 us; speedup vs baseline: 1.7606x; 1.0350x over previous
//
#include <hip/hip_runtime.h>
#include <hip/hip_bf16.h>
#include <math.h>

// Problem constants
#define BATCH   2048
#define TWO_B   4096
#define DIM     1024
#define NBLK4   256           // 16x16 grid of 256x256 tiles
#define RBLK    32            // reduce blocks
// 1 / (0.07 * ln(2)) : exp(s/T) = exp2(s * INV_T_LOG2E)
#define INV_T_LOG2E 20.60991907f
#define INV_T       14.285714285714286f
#define INV_127SQ   6.200013640958517e-05f   // 1/(127*127)

typedef float f32x4 __attribute__((ext_vector_type(4)));
typedef int   i32x4 __attribute__((ext_vector_type(4)));

// R24: k-tiled z layout. R22+R23 verdict: the no-staging K-loop runs at
// ~90% of the i8 MFMA roofline (X~10 us vs 8.7 floor; MfmaUtil 11% is
// gfx94x-formula miscalibration); the ~24 us residual is staging
// THROUGHPUT (drain->counted-vmcnt changed nothing). Mechanism: each
// global_load_lds touches 16 scattered 64-B lines (rows 1 KB apart),
// serviced at ~6 cyc/line (fits R19's 3x-line-count = 61 us too).
// Fix: z_t[rowblk][ktile][16KB] tiling so every staging instruction is
// 1 KB fully contiguous; fetch-side XOR swizzle PRE-APPLIED at write
// (seg s^m, m=((row&15)>>1)&3) making the staged LDS image bit-identical
// to R23. GEMM compute/epilogue and reduce unchanged.
__device__ __attribute__((aligned(4096))) char g_z[(size_t)TWO_B * DIM]; // i8 tiled, 4 MB
__device__ __attribute__((aligned(256))) float g_part[TWO_B][32];        // 512 KB
__device__ float        g_positives[TWO_B];
__device__ float        g_loss;
__device__ unsigned int g_counter;

__device__ __forceinline__ void load_lds16(const void* g, void* l) {
    __builtin_amdgcn_global_load_lds(
        (const __attribute__((address_space(1))) void*)g,
        (__attribute__((address_space(3))) void*)l,
        16, 0, 0);
}

// ---------------------------------------------------------------------------
// Kernel 1: L2-normalize 4096 rows -> int8, written in the k-tiled +
// pre-swizzled layout: lane's 16 B (k-slice kt=lane>>2, seg s=lane&3) goes to
//   z_t[(row>>8)*16 + kt][ (row>>4)&15 ][ row&15 ][ s ^ ((row&15)>>1)&3 ]
// (slab 16 KB, chunk 1 KB, row-in-chunk 64 B, seg 16 B).
// ---------------------------------------------------------------------------
__global__ __launch_bounds__(256) void normalize_kernel(
        const float* __restrict__ feat) {
    const int lane = threadIdx.x & 63;
    const int row  = blockIdx.x * 4 + (threadIdx.x >> 6);
    if (blockIdx.x == 0 && threadIdx.x == 0) { g_loss = 0.0f; g_counter = 0u; }

    const float* src = feat + (row < BATCH ? (size_t)row * (2 * DIM)
                                           : (size_t)(row - BATCH) * (2 * DIM) + DIM);
    float4 v[4];
    float ss = 0.0f;
    #pragma unroll
    for (int t = 0; t < 4; ++t) {
        v[t] = ((const float4*)src)[t * 64 + lane];
        ss += v[t].x * v[t].x + v[t].y * v[t].y + v[t].z * v[t].z + v[t].w * v[t].w;
    }
    #pragma unroll
    for (int off = 32; off; off >>= 1) ss += __shfl_xor(ss, off, 64);
    const float s127 = 127.0f / fmaxf(sqrtf(ss), 1e-12f);
    int4 o;
    int* op = (int*)&o;
    #pragma unroll
    for (int t = 0; t < 4; ++t) {
        const int b0 = __float2int_rn(v[t].x * s127) & 255;
        const int b1 = __float2int_rn(v[t].y * s127) & 255;
        const int b2 = __float2int_rn(v[t].z * s127) & 255;
        const int b3 = __float2int_rn(v[t].w * s127) & 255;
        op[t] = b0 | (b1 << 8) | (b2 << 16) | (b3 << 24);
    }
    // tiled + pre-swizzled store
    const int kt = lane >> 2;                 // k-tile 0..15
    const int s  = lane & 3;                  // 16-B seg within 64-B slice
    const int rl = row & 15;                  // row within chunk
    const int m  = (rl >> 1) & 3;             // fetch-XOR selector
    const size_t off = ((size_t)((row >> 8) * 16 + kt) << 14)
                     + ((size_t)((row >> 4) & 15) << 10)
                     + (rl << 6) + ((s ^ m) << 4);
    *(int4*)(g_z + off) = o;
}

// ---------------------------------------------------------------------------
// Kernel 2 (R24): sim = (q q^T)/127^2 via mfma_i32_16x16x64_i8.
// R23 body (3-buffer, depth-2 prefetch, counted vmcnt) with goff switched
// to the tiled layout: each staging instruction reads 1 KB CONTIGUOUS from
// slab ((isB?bx:by)*16 + kt); per-tile advance = +16384. LDS image, rslot
// read swizzle, MFMA order, epilogue: bit-identical to R23 (absmax 0.0).
// ---------------------------------------------------------------------------
__global__ __launch_bounds__(512) void gemm_fused() {
    __shared__ char smem[98304];     // 3 buffers x 32 KB [sA 16K | sB 16K]

    // XCD-aware swizzle: id&7 = round-robin XCD; 4x8-tile region per XCD
    const int bid = blockIdx.x;
    const int xcd = bid & 7;
    const int t5  = bid >> 3;                   // 0..31 within region
    const int by  = (xcd >> 1) * 4 + (t5 & 3);
    const int bx  = (xcd & 1) * 8 + (t5 >> 2);
    const int rb  = by * 256;
    const int cb  = bx * 256;

    const int tid  = threadIdx.x;
    const int lane = tid & 63;
    const int wv   = tid >> 6;       // wave 0..7
    const int wr   = wv & 3;         // wave row (0..3) -> 64-row subtile
    const int wc   = wv >> 2;        // wave col (0..1) -> 128-col subtile
    const int q    = lane >> 4;      // quad 0..3
    const int mn   = lane & 15;

    i32x4 acc[4][8] = {};            // i32 accumulators (exact)

    const int rslot = (q ^ ((mn >> 1) & 3)) * 16;      // LDS read XOR (unchanged)

    // staging: 32 chunks of 1 KB (A: ci 0..15 from slab by*16+kt,
    // B: ci 16..31 from slab bx*16+kt); wave wv stages ci = 4wv..4wv+3.
    // goff = slab-local contiguous offset; per-tile advance = +16384.
    size_t goff[4];
    int    loff[4];
    #pragma unroll
    for (int t = 0; t < 4; ++t) {
        const int ci = wv * 4 + t;
        const bool isB = ci >= 16;
        const int  cc  = ci & 15;
        goff[t] = ((size_t)((isB ? bx : by) * 16) << 14)   // slab base (kt=0)
                + ((size_t)cc << 10) + (size_t)lane * 16;
        loff[t] = (isB ? 16384 : 0) + cc * 1024;
    }

    // ---- prologue: stage tiles 0,1 into buffers 0,1; wait tile 0 only ----
    #pragma unroll
    for (int b = 0; b < 2; ++b)
        #pragma unroll
        for (int t = 0; t < 4; ++t)
            load_lds16(g_z + goff[t] + (size_t)b * 16384, smem + b * 32768 + loff[t]);
    asm volatile("s_waitcnt vmcnt(4)" ::: "memory");   // tile 0 resident
    __builtin_amdgcn_s_barrier();

    int cur = 0;                     // buffer holding tile t
    for (int t = 0; t < 16; ++t) {
        const char* cA = smem + cur * 32768;
        const char* cB = cA + 16384;

        i32x4 af[4], bf[8];
        #pragma unroll
        for (int i = 0; i < 4; ++i)
            af[i] = *(const i32x4*)&cA[(wr * 64 + i * 16 + mn) * 64 + rslot];
        #pragma unroll
        for (int j = 0; j < 8; ++j)
            bf[j] = *(const i32x4*)&cB[(wc * 128 + j * 16 + mn) * 64 + rslot];

        if (t + 2 < 16) {            // stage tile t+2 into buf (cur+2)%3
            const int bs = cur >= 1 ? cur - 1 : 2;
            #pragma unroll
            for (int tt = 0; tt < 4; ++tt)
                load_lds16(g_z + goff[tt] + (size_t)(t + 2) * 16384,
                           smem + bs * 32768 + loff[tt]);
        }

        #pragma unroll
        for (int i = 0; i < 4; ++i)
            #pragma unroll
            for (int j = 0; j < 8; ++j)
                acc[i][j] = __builtin_amdgcn_mfma_i32_16x16x64_i8(
                                af[i], bf[j], acc[i][j], 0, 0, 0);

        if (t < 15) {
            // tile t+1 must be resident past this barrier; newest in-flight
            // loads are tile t+2's 4 (none issued at t=14 -> drain 0).
            if (t < 14) asm volatile("s_waitcnt vmcnt(4) lgkmcnt(0)" ::: "memory");
            else        asm volatile("s_waitcnt vmcnt(0) lgkmcnt(0)" ::: "memory");
            __builtin_amdgcn_s_barrier();
        }
        cur = cur == 2 ? 0 : cur + 1;
    }

    // ---- Epilogue: exp-sum partials, plain uncontended stores ----
    const int slot = bx * 2 + wc;    // 0..31, unique per (col-tile, half)
    #pragma unroll
    for (int i = 0; i < 4; ++i) {
        #pragma unroll
        for (int reg = 0; reg < 4; ++reg) {
            const int r  = rb + wr * 64 + i * 16 + q * 4 + reg;
            const int pc = (r + BATCH) & (TWO_B - 1);
            float local = 0.0f;
            #pragma unroll
            for (int j = 0; j < 8; ++j) {
                const int c = cb + wc * 128 + j * 16 + mn;
                const float s = (float)acc[i][j][reg] * INV_127SQ;
                if (c == pc)   // unique writer per r across the whole grid
                    g_positives[r] = s;
                local += (c == r) ? 0.0f : exp2f(s * INV_T_LOG2E);
            }
            local += __shfl_xor(local, 1, 64);
            local += __shfl_xor(local, 2, 64);
            local += __shfl_xor(local, 4, 64);
            local += __shfl_xor(local, 8, 64);
            if (mn == 0) g_part[r][slot] = local;   // unique (r, slot)
        }
    }
}

// ---------------------------------------------------------------------------
// Kernel 3: parallel reduce — 32 blocks x 128 threads, one row per thread.
// Finalize tail: 32 agent-scope atomicAdds + relaxed counter (proven).
// ---------------------------------------------------------------------------
__global__ __launch_bounds__(128) void reduce_kernel(float* __restrict__ out) {
    const int tid = threadIdx.x;
    const int r   = blockIdx.x * 128 + tid;
    const float4* pr = (const float4*)g_part[r];
    float s = 0.0f;
    #pragma unroll
    for (int u = 0; u < 8; ++u) {
        const float4 v = pr[u];
        s += v.x + v.y + v.z + v.w;
    }
    float acc = logf(s) - g_positives[r] * INV_T;
    #pragma unroll
    for (int off = 32; off; off >>= 1) acc += __shfl_down(acc, off, 64);
    __shared__ float sp[2];
    __shared__ int amLast;
    if ((tid & 63) == 0) sp[tid >> 6] = acc;
    __syncthreads();
    if (tid == 0) {
        atomicAdd(&g_loss, sp[0] + sp[1]);
        unsigned int old = __hip_atomic_fetch_add(&g_counter, 1u, __ATOMIC_RELAXED,
                                                  __HIP_MEMORY_SCOPE_AGENT);
        amLast = (old == RBLK - 1);
    }
    __syncthreads();
    if (amLast && tid == 0)
        out[0] = __hip_atomic_load(&g_loss, __ATOMIC_RELAXED,
                                   __HIP_MEMORY_SCOPE_AGENT) * (1.0f / TWO_B);
}

extern "C" void kernel_launch(void* const* d_in, const int* in_sizes, int n_in,
                              void* d_out, int out_size, void* d_ws, size_t ws_size,
                              hipStream_t stream) {
    const float* feat = (const float*)d_in[0];
    float* out = (float*)d_out;
    (void)d_ws; (void)ws_size;   // poison fill is unconditional (R14) — ws unused

    normalize_kernel<<<TWO_B / 4, 256, 0, stream>>>(feat);
    gemm_fused<<<NBLK4, 512, 0, stream>>>();
    reduce_kernel<<<RBLK, 128, 0, stream>>>(out);
}